// Round 3
// baseline (61.787 us; speedup 1.0000x reference)
//
#include <hip/hip_runtime.h>

#define NB 36
#define W 640
#define H 640
#define NSAMP 64
#define ROWS_PER_BLK 10
#define SLABS (H / ROWS_PER_BLK)            // 64
#define CHUNKS_PER_ROW (W / 8)              // 80
#define CHUNKS_PER_SLAB (ROWS_PER_BLK * CHUNKS_PER_ROW)  // 800

// Fixed-point scale for mask sums: 2^25. Per-pixel value < 2^25, per-cell sum
// < 409600 * 2^25 < 2^44 -> pack count in bits [44..63), sum in bits [0..44).
#define FIX_SCALE 33554432.0f   // 2^25
#define CNT_SHIFT 44

// Bin assignment emulating the float64 golden:
//   bin = trunc(clip( (atan2(dy,dx) + pi)/(2pi) * 36 ))   [all f64]
// Fast path: f32 atan2f + f32 chain. Its bin agrees with the f64 chain
// whenever binf is > ~1e-5 bin-units from an integer boundary; we use a
// 2e-4 guard band and recompute the FULL f64 chain inside the band.
__device__ __forceinline__ int bin_of(float dx, float dy) {
    const float  PI_F     = 0x1.921fb6p+1f;
    const float  TWOPI_F  = 0x1.921fb6p+2f;
    const double PI_D     = 3.141592653589793;
    const double TWOPI_D  = 6.283185307179586;
    float a  = atan2f(dy, dx);
    float bf = (a + PI_F) / TWOPI_F * 36.0f;
    float fr = bf - floorf(bf);
    int k;
    if (fr < 2e-4f || fr > 1.0f - 2e-4f) {
        double bd = (atan2((double)dy, (double)dx) + PI_D) / TWOPI_D * 36.0;
        k = (int)bd;              // bd >= 0: trunc == floor
    } else {
        k = (int)bf;
    }
    k = k < 0 ? 0 : k;
    return k > (NB - 1) ? (NB - 1) : k;
}

__global__ void acl_zero(unsigned long long* __restrict__ ws) {
    int i = blockIdx.x * 256 + threadIdx.x;
    if (i < NSAMP * NB) ws[i] = 0ull;
}

__global__ __launch_bounds__(256) void acl_main(const float* __restrict__ mask,
                                                const float* __restrict__ bbox,
                                                unsigned long long* __restrict__ ws) {
    __shared__ unsigned long long lbin[NB];
    const int t = threadIdx.x;
    if (t < NB) lbin[t] = 0ull;
    __syncthreads();

    const int sb   = blockIdx.x;       // 0..4095
    const int b    = sb >> 6;          // sample
    const int slab = sb & 63;          // 10-row slab within sample
    const float cx = bbox[b * 4 + 0] * 640.0f;
    const float cy = bbox[b * 4 + 1] * 640.0f;

    const float4* base =
        (const float4*)(mask + (size_t)b * (W * H) + (size_t)slab * ROWS_PER_BLK * W);

    for (int idx = t; idx < CHUNKS_PER_SLAB; idx += 256) {
        const int row = idx / CHUNKS_PER_ROW;
        const int c8  = idx - row * CHUNKS_PER_ROW;
        const int x0  = c8 * 8;
        const int y   = slab * ROWS_PER_BLK + row;
        const float dy = (float)y - cy;

        const float4 v0 = base[idx * 2];
        const float4 v1 = base[idx * 2 + 1];
        const float mv[8] = {v0.x, v0.y, v0.z, v0.w, v1.x, v1.y, v1.z, v1.w};

        // Per-pixel binning (no shortcut); merge consecutive same-bin runs.
        int cur = -1;
        unsigned long long acc = 0, c = 0;
        #pragma unroll
        for (int j = 0; j < 8; j++) {
            const int bj = bin_of((float)(x0 + j) - cx, dy);
            if (bj != cur) {
                if (c) atomicAdd(&lbin[cur], (c << CNT_SHIFT) + acc);
                cur = bj; acc = 0; c = 0;
            }
            acc += (unsigned long long)__float2uint_rn(mv[j] * FIX_SCALE);
            c += 1;
        }
        atomicAdd(&lbin[cur], (c << CNT_SHIFT) + acc);
    }

    __syncthreads();
    if (t < NB) atomicAdd(&ws[b * NB + t], lbin[t]);
}

__global__ void acl_final(const unsigned long long* __restrict__ ws,
                          float* __restrict__ out) {
    __shared__ float s[NSAMP];
    const int b = threadIdx.x;   // one thread per sample, block = 64
    int nunder = 0;
    for (int k = 0; k < NB; k++) {
        const unsigned long long v = ws[b * NB + k];
        const unsigned long long cnt = v >> CNT_SHIFT;
        const float sum = (float)(v & ((1ull << CNT_SHIFT) - 1)) * (1.0f / FIX_SCALE);
        const float act = (cnt != 0ull) ? (sum / (float)cnt) : 0.0f;
        if (act < 0.1f) nunder++;
    }
    s[b] = (float)nunder / 36.0f;
    __syncthreads();
    if (b == 0) {
        float acc = 0.0f;
        for (int i = 0; i < NSAMP; i++) acc += s[i];
        out[0] = acc / 64.0f;   // PENALTY_WEIGHT == 1, float32 output
    }
}

extern "C" void kernel_launch(void* const* d_in, const int* in_sizes, int n_in,
                              void* d_out, int out_size, void* d_ws, size_t ws_size,
                              hipStream_t stream) {
    const float* mask = (const float*)d_in[0];
    const float* bbox = (const float*)d_in[1];
    unsigned long long* ws = (unsigned long long*)d_ws;

    acl_zero<<<dim3((NSAMP * NB + 255) / 256), dim3(256), 0, stream>>>(ws);
    acl_main<<<dim3(NSAMP * SLABS), dim3(256), 0, stream>>>(mask, bbox, ws);
    acl_final<<<dim3(1), dim3(NSAMP), 0, stream>>>(ws, (float*)d_out);
}

// Round 4
// 58.156 us; speedup vs baseline: 1.0624x; 1.0624x over previous
//
#include <hip/hip_runtime.h>
#include <math.h>

#define NB 36
#define W 640
#define H 640
#define NSAMP 64
#define ROWS_PER_BLK 10
#define SLABS (H / ROWS_PER_BLK)            // 64
#define CHUNKS_PER_ROW (W / 8)              // 80
#define CHUNKS_PER_SLAB (ROWS_PER_BLK * CHUNKS_PER_ROW)  // 800

// Fixed-point scale for mask sums: 2^25. Per-cell sum < 409600*2^25 < 2^44
// -> pack count in bits [44..63), sum in bits [0..44).
#define FIX_SCALE 33554432.0f   // 2^25
#define CNT_SHIFT 44

// Guard band in bin units. Fast-path total error <= ~8e-5 bins
// (poly 5.7e-5 + coord/chain roundings ~2e-5). 1e-3 gives >10x margin;
// fallback rate ~2e-3 of pixels (cheap).
#define BAND 1e-3f

// ---- exact golden chain (float64), used only inside the guard band -------
__device__ __forceinline__ int bin_slow(int x, int y, float bx, float by) {
    const double PI_D    = 3.141592653589793;
    const double TWOPI_D = 6.283185307179586;
    double cxd = (double)bx * 640.0;        // exact (24-bit * 640 fits f64)
    double cyd = (double)by * 640.0;
    double dxd = (double)x - cxd;           // exact in f64
    double dyd = (double)y - cyd;
    double t   = (atan2(dyd, dxd) + PI_D) / TWOPI_D;  // replicate op order!
    double bd  = t * 36.0;
    int k = (int)bd;                        // bd >= 0: trunc == floor
    k = k < 0 ? 0 : k;
    return k > NB - 1 ? NB - 1 : k;
}

// ---- fast path: ~25 VALU ops, error well inside BAND ---------------------
// atan(z), z in [0,1]: A&S 4.4.x 5-term odd minimax, |err| ~1e-5 rad.
__device__ __forceinline__ int bin_fast(float dx, float dy, bool& slow) {
    float adx = __builtin_fabsf(dx), ady = __builtin_fabsf(dy);
    float mx = fmaxf(adx, ady), mn = fminf(adx, ady);
    float r0 = __builtin_amdgcn_rcpf(mx);
    float r  = r0 * fmaf(-mx, r0, 2.0f);    // 1 Newton step: ~1e-7 rel
    float z  = mn * r;
    float w  = z * z;
    float p  = fmaf(w, 0.0208351f, -0.0851330f);
    p = fmaf(w, p, 0.1801410f);
    p = fmaf(w, p, -0.3302995f);
    p = fmaf(w, p, 0.9998660f);
    float a = p * z;                        // atan(mn/mx) in [0, pi/4]
    const float PI_F   = 3.14159265f;
    const float PIO2_F = 1.57079633f;
    if (ady > adx) a = PIO2_F - a;          // cndmask, no divergence
    if (dx < 0.0f) a = PI_F - a;
    a = (dy < 0.0f) ? -a : a;
    // binf = (a + pi) * (36 / 2pi) = a * (18/pi) + 18
    float binf = fmaf(a, 5.729577951308232f, 18.0f);
    float fl = floorf(binf);
    float fr = binf - fl;
    slow = slow | (fr < BAND) | (fr > 1.0f - BAND);
    int k = (int)fl;
    k = k < 0 ? 0 : k;
    return k > NB - 1 ? NB - 1 : k;
}

__device__ __forceinline__ int bin_px(int x, int y, float dx, float dy,
                                      float bx, float by) {
    bool slow = (fmaf(dx, dx, dy * dy) < 4.0f);  // near-center: always f64
    int k = bin_fast(dx, dy, slow);
    if (slow) k = bin_slow(x, y, bx, by);        // rare: whole-wave skip
    return k;
}

__global__ void acl_zero(unsigned long long* __restrict__ ws) {
    int i = blockIdx.x * 256 + threadIdx.x;
    if (i < NSAMP * NB) ws[i] = 0ull;
}

__global__ __launch_bounds__(256) void acl_main(const float* __restrict__ mask,
                                                const float* __restrict__ bbox,
                                                unsigned long long* __restrict__ ws) {
    __shared__ unsigned long long lbin[NB];
    const int t = threadIdx.x;
    if (t < NB) lbin[t] = 0ull;
    __syncthreads();

    const int sb   = blockIdx.x;       // 0..4095
    const int b    = sb >> 6;          // sample
    const int slab = sb & 63;          // 10-row slab within sample
    const float bx = bbox[b * 4 + 0];
    const float by = bbox[b * 4 + 1];
    // hi/lo split of the f64-exact centers -> per-pixel coords accurate to
    // ~1 ulp RELATIVE (no absolute 3e-5 px error from f32 cx rounding)
    const double cxd = (double)bx * 640.0;
    const double cyd = (double)by * 640.0;
    const float cx_hi = (float)cxd, cx_lo = (float)(cxd - (double)cx_hi);
    const float cy_hi = (float)cyd, cy_lo = (float)(cyd - (double)cy_hi);

    const float4* base =
        (const float4*)(mask + (size_t)b * (W * H) + (size_t)slab * ROWS_PER_BLK * W);

    for (int idx = t; idx < CHUNKS_PER_SLAB; idx += 256) {
        const int row = idx / CHUNKS_PER_ROW;
        const int c8  = idx - row * CHUNKS_PER_ROW;
        const int x0  = c8 * 8;
        const int y   = slab * ROWS_PER_BLK + row;
        const float dy = ((float)y - cy_hi) - cy_lo;

        const float4 v0 = base[idx * 2];
        const float4 v1 = base[idx * 2 + 1];
        const float mv[8] = {v0.x, v0.y, v0.z, v0.w, v1.x, v1.y, v1.z, v1.w};

        const float dx0 = ((float)x0 - cx_hi) - cx_lo;
        const float dx7 = ((float)(x0 + 7) - cx_hi) - cx_lo;
        const int b0 = bin_px(x0, y, dx0, dy, bx, by);
        const int b7 = bin_px(x0 + 7, y, dx7, dy, bx, by);

        if (b0 == b7) {
            // golden binf is monotone in x along a row (monotone correctly-
            // rounded ops), and endpoints match golden exactly => interior
            // bins are squeezed equal.
            unsigned long long acc = 0;
            #pragma unroll
            for (int j = 0; j < 8; j++)
                acc += (unsigned long long)__float2uint_rn(mv[j] * FIX_SCALE);
            atomicAdd(&lbin[b0], (8ull << CNT_SHIFT) + acc);
        } else {
            int cur = b0;
            unsigned long long acc = 0, c = 0;
            #pragma unroll
            for (int j = 0; j < 8; j++) {
                int bj;
                if (j == 0) bj = b0;
                else if (j == 7) bj = b7;
                else {
                    const float dxj = ((float)(x0 + j) - cx_hi) - cx_lo;
                    bj = bin_px(x0 + j, y, dxj, dy, bx, by);
                }
                if (bj != cur) {
                    atomicAdd(&lbin[cur], (c << CNT_SHIFT) + acc);
                    cur = bj; acc = 0; c = 0;
                }
                acc += (unsigned long long)__float2uint_rn(mv[j] * FIX_SCALE);
                c += 1;
            }
            atomicAdd(&lbin[cur], (c << CNT_SHIFT) + acc);
        }
    }

    __syncthreads();
    if (t < NB) atomicAdd(&ws[b * NB + t], lbin[t]);
}

__global__ void acl_final(const unsigned long long* __restrict__ ws,
                          float* __restrict__ out) {
    __shared__ float s[NSAMP];
    const int b = threadIdx.x;   // one thread per sample, block = 64
    int nunder = 0;
    for (int k = 0; k < NB; k++) {
        const unsigned long long v = ws[b * NB + k];
        const unsigned long long cnt = v >> CNT_SHIFT;
        const float sum = (float)(v & ((1ull << CNT_SHIFT) - 1)) * (1.0f / FIX_SCALE);
        const float act = (cnt != 0ull) ? (sum / (float)cnt) : 0.0f;
        if (act < 0.1f) nunder++;
    }
    s[b] = (float)nunder / 36.0f;
    __syncthreads();
    if (b == 0) {
        float acc = 0.0f;
        for (int i = 0; i < NSAMP; i++) acc += s[i];
        out[0] = acc / 64.0f;   // PENALTY_WEIGHT == 1, float32 output
    }
}

extern "C" void kernel_launch(void* const* d_in, const int* in_sizes, int n_in,
                              void* d_out, int out_size, void* d_ws, size_t ws_size,
                              hipStream_t stream) {
    const float* mask = (const float*)d_in[0];
    const float* bbox = (const float*)d_in[1];
    unsigned long long* ws = (unsigned long long*)d_ws;

    acl_zero<<<dim3((NSAMP * NB + 255) / 256), dim3(256), 0, stream>>>(ws);
    acl_main<<<dim3(NSAMP * SLABS), dim3(256), 0, stream>>>(mask, bbox, ws);
    acl_final<<<dim3(1), dim3(NSAMP), 0, stream>>>(ws, (float*)d_out);
}

// Round 5
// 57.532 us; speedup vs baseline: 1.0740x; 1.0108x over previous
//
#include <hip/hip_runtime.h>
#include <math.h>

#define NB 36
#define W 640
#define H 640
#define NSAMP 64
#define FIX_SCALE 33554432.0f   // 2^25
#define CNT_SHIFT 44
#define AMB 1e-6

// Exact f64 golden chain (empirically verified: absmax==0 in rounds 3/4).
__device__ __forceinline__ int bin_slow(int x, int y, double cxd, double cyd) {
    const double PI_D    = 3.141592653589793;
    const double TWOPI_D = 6.283185307179586;
    double dxd = (double)x - cxd;
    double dyd = (double)y - cyd;
    double t  = (atan2(dyd, dxd) + PI_D) / TWOPI_D;
    double bd = t * 36.0;
    int k = (int)bd;
    k = k < 0 ? 0 : k;
    return k > NB - 1 ? NB - 1 : k;
}

// zero histogram + build cot table: tbl[m] = cot((m-18)*pi/18), m != 18
__global__ void acl_setup(unsigned long long* __restrict__ ws) {
    int i = blockIdx.x * 256 + threadIdx.x;
    if (i < NSAMP * NB) ws[i] = 0ull;
    if (blockIdx.x == 0 && threadIdx.x < NB) {
        double* tbl = (double*)(ws + NSAMP * NB);
        int m = threadIdx.x;
        double t = 0.0;
        if (m != 18) {
            double th = (double)(m - 18) * (3.141592653589793 / 18.0);
            t = cos(th) / sin(th);
        }
        tbl[m] = t;
    }
}

__global__ __launch_bounds__(256) void acl_main(const float* __restrict__ mask,
                                                const float* __restrict__ bbox,
                                                unsigned long long* __restrict__ ws) {
    __shared__ unsigned long long lbin[NB];
    __shared__ int sbnd[4][17];
    const int tid = threadIdx.x;
    const int b   = blockIdx.x / 160;   // sample
    const int rg  = blockIdx.x % 160;   // row group (4 rows)
    if (tid < NB) lbin[tid] = 0ull;

    const double cxd = (double)bbox[b * 4 + 0] * 640.0;   // f64-exact
    const double cyd = (double)bbox[b * 4 + 1] * 640.0;
    const double* tbl = (const double*)(ws + NSAMP * NB);

    // ---- phase 1: 68 boundary tasks (17 per row x 4 rows), parallel ------
    if (tid < 68) {
        const int ri = tid / 17, mi = tid % 17;
        const int y  = rg * 4 + ri;
        const double dy = (double)y - cyd;
        const int m  = (dy > 0.0) ? (19 + mi) : (1 + mi);
        double x = cxd + dy * tbl[m];
        x = fmin(fmax(x, -2.0), 642.0);
        double g  = x + 2.0;                 // g in [0,644]: trunc == floor
        int    gi = (int)g;
        double fr = g - (double)gi;
        int v = (dy > 0.0) ? (gi - 2)        // floor(x):  pixels <= v have bin >= m
                           : (gi - 1);       // ceil(x):   pixels >= v have bin >= m
        if (fr < AMB || fr > 1.0 - AMB) {    // boundary razor-close to a pixel
            int xa = (int)(x + 2.5) - 2;     // nearest integer
            if (xa >= 0 && xa <= W - 1) {
                int kb = bin_slow(xa, y, cxd, cyd);   // exact golden decision
                if (dy > 0.0) v = (kb >= m) ? xa : xa - 1;
                else          v = (kb >= m) ? xa : xa + 1;
            }
        }
        sbnd[ri][mi] = v;
    }
    __syncthreads();

    // ---- phase 2: one wave per row, compare-count binning ----------------
    const int wid = tid >> 6, lane = tid & 63;
    const int y   = rg * 4 + wid;
    const double dy = (double)y - cyd;
    const bool dpos = (dy > 0.0), dneg = (dy < 0.0);
    int sb[17];
    #pragma unroll
    for (int m = 0; m < 17; m++) sb[m] = sbnd[wid][m];

    const float4* rowp =
        (const float4*)(mask + (size_t)b * (W * H) + (size_t)y * W);

    #pragma unroll
    for (int s = 0; s < 3; s++) {
        if (s < 2 || lane < 32) {            // 160 float4 = 64+64+32
            const int fi = lane + 64 * s;
            const int x0 = 4 * fi;
            const float4 v = rowp[fi];
            const unsigned q0 = __float2uint_rn(v.x * FIX_SCALE);
            const unsigned q1 = __float2uint_rn(v.y * FIX_SCALE);
            const unsigned q2 = __float2uint_rn(v.z * FIX_SCALE);
            const unsigned q3 = __float2uint_rn(v.w * FIX_SCALE);

            int b0, b1, b2, b3;
            if (dpos) {                      // bin = 18 + #{m: x <= s_m}
                b0 = 18; b1 = 18; b2 = 18; b3 = 18;
                #pragma unroll
                for (int m = 0; m < 17; m++) {
                    const int sm = sb[m];
                    b0 += (x0     <= sm); b1 += (x0 + 1 <= sm);
                    b2 += (x0 + 2 <= sm); b3 += (x0 + 3 <= sm);
                }
            } else if (dneg) {               // bin = #{m: x >= c_m}
                b0 = 0; b1 = 0; b2 = 0; b3 = 0;
                #pragma unroll
                for (int m = 0; m < 17; m++) {
                    const int cm = sb[m];
                    b0 += (x0     >= cm); b1 += (x0 + 1 >= cm);
                    b2 += (x0 + 2 >= cm); b3 += (x0 + 3 >= cm);
                }
            } else {                         // dy == 0: angle is 0 or pi
                b0 = ((double)(x0    ) >= cxd) ? 18 : 35;
                b1 = ((double)(x0 + 1) >= cxd) ? 18 : 35;
                b2 = ((double)(x0 + 2) >= cxd) ? 18 : 35;
                b3 = ((double)(x0 + 3) >= cxd) ? 18 : 35;
            }

            // merge same-bin runs within the 4 pixels, LDS atomics per run
            unsigned long long acc = q0;
            unsigned c = 1;
            int cur = b0;
            if (b1 != cur) {
                atomicAdd(&lbin[cur], ((unsigned long long)c << CNT_SHIFT) + acc);
                cur = b1; acc = 0; c = 0;
            }
            acc += q1; c++;
            if (b2 != cur) {
                atomicAdd(&lbin[cur], ((unsigned long long)c << CNT_SHIFT) + acc);
                cur = b2; acc = 0; c = 0;
            }
            acc += q2; c++;
            if (b3 != cur) {
                atomicAdd(&lbin[cur], ((unsigned long long)c << CNT_SHIFT) + acc);
                cur = b3; acc = 0; c = 0;
            }
            acc += q3; c++;
            atomicAdd(&lbin[cur], ((unsigned long long)c << CNT_SHIFT) + acc);
        }
    }

    __syncthreads();
    if (tid < NB) atomicAdd(&ws[b * NB + tid], lbin[tid]);
}

__global__ void acl_final(const unsigned long long* __restrict__ ws,
                          float* __restrict__ out) {
    __shared__ float s[NSAMP];
    const int b = threadIdx.x;   // one thread per sample, block = 64
    int nunder = 0;
    for (int k = 0; k < NB; k++) {
        const unsigned long long v = ws[b * NB + k];
        const unsigned long long cnt = v >> CNT_SHIFT;
        const float sum = (float)(v & ((1ull << CNT_SHIFT) - 1)) * (1.0f / FIX_SCALE);
        const float act = (cnt != 0ull) ? (sum / (float)cnt) : 0.0f;
        if (act < 0.1f) nunder++;
    }
    s[b] = (float)nunder / 36.0f;
    __syncthreads();
    if (b == 0) {
        float acc = 0.0f;
        for (int i = 0; i < NSAMP; i++) acc += s[i];
        out[0] = acc / 64.0f;   // PENALTY_WEIGHT == 1, float32 output
    }
}

extern "C" void kernel_launch(void* const* d_in, const int* in_sizes, int n_in,
                              void* d_out, int out_size, void* d_ws, size_t ws_size,
                              hipStream_t stream) {
    const float* mask = (const float*)d_in[0];
    const float* bbox = (const float*)d_in[1];
    unsigned long long* ws = (unsigned long long*)d_ws;

    acl_setup<<<dim3((NSAMP * NB + 255) / 256), dim3(256), 0, stream>>>(ws);
    acl_main<<<dim3(NSAMP * 160), dim3(256), 0, stream>>>(mask, bbox, ws);
    acl_final<<<dim3(1), dim3(NSAMP), 0, stream>>>(ws, (float*)d_out);
}